// Round 12
// baseline (80.567 us; speedup 1.0000x reference)
//
#include <hip/hip_runtime.h>
#include <math.h>

#define BATCH 256
#define CLS 500
#define T_TEMP_ 10.0f
#define THRESH_ 0.86602540378443864676f
#define NEGV -9.0e15f
#define CAP 16

typedef __attribute__((ext_vector_type(8))) short short8;
typedef __attribute__((ext_vector_type(8))) unsigned short u16x8;
typedef __attribute__((ext_vector_type(4))) unsigned short u16x4;
typedef __attribute__((ext_vector_type(4))) float f32x4;
typedef __attribute__((ext_vector_type(2))) float f32x2;

static __device__ __forceinline__ unsigned short f2bf(float x) {
    unsigned int u = __builtin_bit_cast(unsigned int, x);
    u += 0x7fff + ((u >> 16) & 1);
    return (unsigned short)(u >> 16);
}
static __device__ __forceinline__ float bf2f(unsigned short v) {
    return __builtin_bit_cast(float, (unsigned int)v << 16);
}
static __device__ __forceinline__ float fel(const float4& v, int j) { return (&v.x)[j]; }
static __device__ __forceinline__ u16x8 pack8(const float4& a, const float4& b) {
    u16x8 o;
    o[0] = f2bf(a.x); o[1] = f2bf(a.y); o[2] = f2bf(a.z); o[3] = f2bf(a.w);
    o[4] = f2bf(b.x); o[5] = f2bf(b.y); o[6] = f2bf(b.z); o[7] = f2bf(b.w);
    return o;
}

// =============== KA: fused dual GEMM dispatch (320 blocks) ===============
// bid < 128: family G = g split-K partials (r11 gpart_kernel, verbatim body).
// bid >= 128: family H = hid0 partials, rows [imgf(256); attrs(500)] @ [imgw; semw]
//             (r11 hid_kernel body; sem A-side is attrs f32 — attention applied later in KD).
__global__ __launch_bounds__(256) void ka_kernel(
    const float* __restrict__ attrs, const float* __restrict__ attg,
    const float* __restrict__ imgf, const float* __restrict__ imgw,
    const float* __restrict__ semw,
    float* __restrict__ gpart, unsigned short* __restrict__ hid0)
{
    __shared__ unsigned short As[64][40];
    __shared__ unsigned short Bs[128][40];
    const int t = threadIdx.x;
    const int bid = blockIdx.x;

    const int w = t >> 6, lane = t & 63;
    const int wr = w >> 1, wc = w & 1;
    const int fr = lane & 15, kg = lane >> 4;
    const int as_row = t >> 2, as_kq = t & 3;
    const int bs_nc = (t & 31) * 4, bs_kr = t >> 5;

    f32x4 acc[2][4];
    #pragma unroll
    for (int i = 0; i < 2; ++i)
        #pragma unroll
        for (int j = 0; j < 4; ++j) acc[i][j] = (f32x4){0.f, 0.f, 0.f, 0.f};

    if (bid < 128) {
        // ---- family G: g = attrs @ att_g, split-K 8, klen=128 ----
        const int mt = bid >> 4, nt = (bid >> 3) & 1, split = bid & 7;
        const int n0 = nt * 128, ar0 = mt * 64, k0 = split * 128;

        for (int kb = k0; kb < k0 + 128; kb += 32) {
            {   // A stage: attrs f32 -> bf16
                const int gr = ar0 + as_row;
                float4 v0 = make_float4(0.f,0.f,0.f,0.f), v1 = v0;
                if (gr < CLS) {
                    const float* ap = &attrs[(size_t)gr * 1024 + kb + as_kq * 8];
                    v0 = *(const float4*)ap; v1 = *(const float4*)(ap + 4);
                }
                *(u16x8*)&As[as_row][as_kq * 8] = pack8(v0, v1);
            }
            {   // B stage: attg f32 [1024][256] row-major -> Bs[n][k]
                const float* bp = &attg[(size_t)(kb + bs_kr * 4) * 256 + n0 + bs_nc];
                float4 r0 = *(const float4*)(bp);
                float4 r1 = *(const float4*)(bp + 256);
                float4 r2 = *(const float4*)(bp + 512);
                float4 r3 = *(const float4*)(bp + 768);
                #pragma unroll
                for (int j = 0; j < 4; ++j) {
                    unsigned int lo = (unsigned int)f2bf(fel(r0, j)) | ((unsigned int)f2bf(fel(r1, j)) << 16);
                    unsigned int hi = (unsigned int)f2bf(fel(r2, j)) | ((unsigned int)f2bf(fel(r3, j)) << 16);
                    uint2 u2; u2.x = lo; u2.y = hi;
                    *(uint2*)&Bs[bs_nc + j][bs_kr * 4] = u2;
                }
            }
            __syncthreads();
            short8 af[2], bfr[4];
            #pragma unroll
            for (int i = 0; i < 2; ++i) af[i] = *(short8*)&As[wr * 32 + i * 16 + fr][kg * 8];
            #pragma unroll
            for (int j = 0; j < 4; ++j) bfr[j] = *(short8*)&Bs[wc * 64 + j * 16 + fr][kg * 8];
            #pragma unroll
            for (int i = 0; i < 2; ++i)
                #pragma unroll
                for (int j = 0; j < 4; ++j)
                    acc[i][j] = __builtin_amdgcn_mfma_f32_16x16x32_bf16(af[i], bfr[j], acc[i][j], 0, 0, 0);
            __syncthreads();
        }

        float* Gp = gpart + (size_t)split * (512 * 256);
        const int orow0 = ar0 + wr * 32, ocol0 = n0 + wc * 64;
        #pragma unroll
        for (int i = 0; i < 2; ++i) {
            const int r0 = orow0 + i * 16 + kg * 4;
            #pragma unroll
            for (int j = 0; j < 4; ++j) {
                const int cc = ocol0 + j * 16 + fr;
                #pragma unroll
                for (int r = 0; r < 4; ++r)
                    Gp[(size_t)(r0 + r) * 256 + cc] = acc[i][j][r];
            }
        }
    } else {
        // ---- family H: hid0 partials, split-K 2, klen=512 ----
        const int idx = bid - 128;
        const int split = idx & 1, nt = (idx >> 1) & 7, mt = idx >> 4;
        const int n0 = nt * 128, k0 = split * 512;
        const bool img_side = (mt < 4);
        const float* Af = img_side ? imgf : attrs;
        const int ar0 = img_side ? mt * 64 : (mt - 4) * 64;
        const int alim = img_side ? 256 : 500;
        const float* Bf = img_side ? imgw : semw;

        for (int kb = k0; kb < k0 + 512; kb += 32) {
            {   // A stage: f32 -> bf16 (uniform path, both sides f32)
                const int gr = ar0 + as_row;
                float4 v0 = make_float4(0.f,0.f,0.f,0.f), v1 = v0;
                if (gr < alim) {
                    const float* ap = &Af[(size_t)gr * 1024 + kb + as_kq * 8];
                    v0 = *(const float4*)ap; v1 = *(const float4*)(ap + 4);
                }
                *(u16x8*)&As[as_row][as_kq * 8] = pack8(v0, v1);
            }
            {   // B stage: f32 [1024][1024] row-major -> Bs[n][k]
                const float* bp = &Bf[(size_t)(kb + bs_kr * 4) * 1024 + n0 + bs_nc];
                float4 r0 = *(const float4*)(bp);
                float4 r1 = *(const float4*)(bp + 1024);
                float4 r2 = *(const float4*)(bp + 2048);
                float4 r3 = *(const float4*)(bp + 3072);
                #pragma unroll
                for (int j = 0; j < 4; ++j) {
                    unsigned int lo = (unsigned int)f2bf(fel(r0, j)) | ((unsigned int)f2bf(fel(r1, j)) << 16);
                    unsigned int hi = (unsigned int)f2bf(fel(r2, j)) | ((unsigned int)f2bf(fel(r3, j)) << 16);
                    uint2 u2; u2.x = lo; u2.y = hi;
                    *(uint2*)&Bs[bs_nc + j][bs_kr * 4] = u2;
                }
            }
            __syncthreads();
            short8 af[2], bfr[4];
            #pragma unroll
            for (int i = 0; i < 2; ++i) af[i] = *(short8*)&As[wr * 32 + i * 16 + fr][kg * 8];
            #pragma unroll
            for (int j = 0; j < 4; ++j) bfr[j] = *(short8*)&Bs[wc * 64 + j * 16 + fr][kg * 8];
            #pragma unroll
            for (int i = 0; i < 2; ++i)
                #pragma unroll
                for (int j = 0; j < 4; ++j)
                    acc[i][j] = __builtin_amdgcn_mfma_f32_16x16x32_bf16(af[i], bfr[j], acc[i][j], 0, 0, 0);
            __syncthreads();
        }

        unsigned short* Cw = hid0 + (size_t)split * (756 * 1024);
        const int orow0 = mt * 64 + wr * 32, ocol0 = n0 + wc * 64;
        #pragma unroll
        for (int i = 0; i < 2; ++i) {
            const int r0 = orow0 + i * 16 + kg * 4;
            #pragma unroll
            for (int j = 0; j < 4; ++j) {
                const int cc = ocol0 + j * 16 + fr;
                #pragma unroll
                for (int r = 0; r < 4; ++r) {
                    const int rr = r0 + r;
                    if (rr < 756) Cw[(size_t)rr * 1024 + cc] = f2bf(acc[i][j][r]);
                }
            }
        }
    }
}

// =============== KB: reduce 8 partials + row-normalize -> gn bf16 (r11-verified) ===============
__global__ __launch_bounds__(256) void reduce_norm_kernel(
    const float* __restrict__ part, unsigned short* __restrict__ gn_bf)
{
    const int c = blockIdx.x, t = threadIdx.x;
    float v = 0.f;
    #pragma unroll
    for (int z = 0; z < 8; ++z) v += part[(size_t)z * (512 * 256) + c * 256 + t];
    float ss = v * v;
    #pragma unroll
    for (int off = 32; off >= 1; off >>= 1) ss += __shfl_down(ss, off);
    __shared__ float red[4];
    const int wave = t >> 6, lane = t & 63;
    if (lane == 0) red[wave] = ss;
    __syncthreads();
    const float tot = red[0] + red[1] + red[2] + red[3];
    const float rn  = 1.f / sqrtf(tot);
    gn_bf[c * 256 + t] = f2bf(v * rn);
}

// =============== KC: sim = gn @ gn^T (r11-verified mfma_gemm_bf, fixed-shape use) ===============
__global__ __launch_bounds__(256) void sim_kernel(
    const unsigned short* __restrict__ gn, float* __restrict__ S)
{
    __shared__ unsigned short As[64][40];
    __shared__ unsigned short Bs[128][40];
    const int t  = threadIdx.x;
    const int n0 = blockIdx.y * 128;
    const int ar0 = blockIdx.x * 64;

    const int w = t >> 6, lane = t & 63;
    const int wr = w >> 1, wc = w & 1;
    const int fr = lane & 15, kg = lane >> 4;
    const int a_row = t >> 2, a_k = (t & 3) * 8;
    const int b_row = t >> 1, b_k = (t & 1) * 16;
    const int gra = ar0 + a_row;
    const int grb = n0 + b_row;
    const bool va = gra < CLS;
    const bool vb = grb < CLS;
    const size_t abase = (size_t)gra * 256 + a_k;
    const size_t bbase = (size_t)grb * 256 + b_k;

    u16x8 zz = {0,0,0,0,0,0,0,0};
    u16x8 pa = zz, pb0 = zz, pb1 = zz;
    if (va) pa = *(const u16x8*)&gn[abase];
    if (vb) { pb0 = *(const u16x8*)&gn[bbase]; pb1 = *(const u16x8*)&gn[bbase + 8]; }

    f32x4 acc[2][4];
    #pragma unroll
    for (int i = 0; i < 2; ++i)
        #pragma unroll
        for (int j = 0; j < 4; ++j) acc[i][j] = (f32x4){0.f, 0.f, 0.f, 0.f};

    for (int kb = 0; kb < 256; kb += 32) {
        *(u16x8*)&As[a_row][a_k] = pa;
        *(u16x8*)&Bs[b_row][b_k] = pb0;
        *(u16x8*)&Bs[b_row][b_k + 8] = pb1;
        __syncthreads();

        const int kn = kb + 32;
        if (kn < 256) {
            if (va) pa = *(const u16x8*)&gn[abase + kn];
            if (vb) { pb0 = *(const u16x8*)&gn[bbase + kn]; pb1 = *(const u16x8*)&gn[bbase + kn + 8]; }
        }

        short8 af[2], bfr[4];
        #pragma unroll
        for (int i = 0; i < 2; ++i) af[i] = *(short8*)&As[wr * 32 + i * 16 + fr][kg * 8];
        #pragma unroll
        for (int j = 0; j < 4; ++j) bfr[j] = *(short8*)&Bs[wc * 64 + j * 16 + fr][kg * 8];
        #pragma unroll
        for (int i = 0; i < 2; ++i)
            #pragma unroll
            for (int j = 0; j < 4; ++j)
                acc[i][j] = __builtin_amdgcn_mfma_f32_16x16x32_bf16(af[i], bfr[j], acc[i][j], 0, 0, 0);
        __syncthreads();
    }

    const int orow0 = ar0 + wr * 32, ocol0 = n0 + wc * 64;
    #pragma unroll
    for (int i = 0; i < 2; ++i) {
        const int r0 = orow0 + i * 16 + kg * 4;
        #pragma unroll
        for (int j = 0; j < 4; ++j) {
            const int cc = ocol0 + j * 16 + fr;
            if (cc >= CLS) continue;
            #pragma unroll
            for (int r = 0; r < 4; ++r) {
                const int rr = r0 + r;
                if (rr < CLS) S[(size_t)rr * CLS + cc] = acc[i][j][r];
            }
        }
    }
}

// =============== KD: in-block softmax + sparse sem gather + fused relu-reduction ===============
// grid (4,8,8): b0, c0, h-chunk. Phase 1 builds per-row hit lists from sim (wave/row);
// phase 2 = r11-verified fused body with sem staging gathered from hid0_sem rows.
__global__ __launch_bounds__(256) void fused_kernel(
    const float* __restrict__ sim, const unsigned short* __restrict__ hid0,
    const float* __restrict__ sem_b, const float* __restrict__ fc_w,
    float* __restrict__ outpart)
{
    __shared__ float imgs[64][68];
    __shared__ float sems[64][68];
    __shared__ float fcs[128];
    __shared__ int   cnt_s[64];
    __shared__ int   hitc2[64][CAP];
    __shared__ float hitw[64][CAP];
    __shared__ float mrow[64];
    __shared__ float invrow[64];

    const size_t pstride = (size_t)756 * 1024;
    const int t  = threadIdx.x;
    const int tb = t >> 4, tc = t & 15;
    const int b0 = blockIdx.x * 64, c0 = blockIdx.y * 64;
    const int h0 = blockIdx.z * 128;
    const int w = t >> 6, lane = t & 63;

    if (t < 32) *(float4*)&fcs[t * 4] = *(const float4*)&fc_w[h0 + t * 4];

    // ---- phase 1: softmax weights for rows c0..c0+63 (wave w owns rows w*16..+16) ----
    for (int i = 0; i < 16; ++i) {
        const int rl = w * 16 + i;
        const int r  = c0 + rl;
        float vals[8];
        float vmax = NEGV;
        if (r < CLS) {
            #pragma unroll
            for (int ch = 0; ch < 8; ++ch) {
                const int c2 = ch * 64 + lane;
                const float d = (c2 < CLS) ? sim[(size_t)r * CLS + c2] : NEGV;
                vals[ch] = d;
                vmax = fmaxf(vmax, (d > THRESH_) ? d : NEGV);
            }
        } else {
            #pragma unroll
            for (int ch = 0; ch < 8; ++ch) vals[ch] = NEGV;
        }
        #pragma unroll
        for (int off = 32; off >= 1; off >>= 1) vmax = fmaxf(vmax, __shfl_down(vmax, off));
        vmax = __shfl(vmax, 0);
        float pvs[8];
        float s = 0.f;
        #pragma unroll
        for (int ch = 0; ch < 8; ++ch) {
            const float pv = (vals[ch] > THRESH_) ? expf(T_TEMP_ * (vals[ch] - vmax)) : 0.f;
            pvs[ch] = pv; s += pv;
        }
        #pragma unroll
        for (int off = 32; off >= 1; off >>= 1) s += __shfl_down(s, off);
        s = __shfl(s, 0);
        const float inv = (r < CLS) ? 1.f / s : 0.f;
        int count = 0;
        #pragma unroll
        for (int ch = 0; ch < 8; ++ch) {
            unsigned long long mk = __ballot(pvs[ch] > 0.f);
            while (mk) {
                const int l = __ffsll((long long)mk) - 1;
                mk &= mk - 1;
                const float wgt = __shfl(pvs[ch], l) * inv;
                if (count < CAP && lane == 0) {
                    hitc2[rl][count] = ch * 64 + l;
                    hitw[rl][count]  = wgt;
                }
                ++count;
            }
        }
        if (lane == 0) { cnt_s[rl] = count; mrow[rl] = vmax; invrow[rl] = inv; }
    }
    __syncthreads();

    // ---- phase 2: r11-verified fused relu-reduction, sem staging via gather ----
    f32x2 acc2[4][4];
    #pragma unroll
    for (int i = 0; i < 4; ++i)
        #pragma unroll
        for (int j = 0; j < 4; ++j) acc2[i][j] = (f32x2){0.f, 0.f};

    for (int hs = 0; hs < 2; ++hs) {
        const int hb = h0 + hs * 64;
        #pragma unroll
        for (int i = 0; i < 4; ++i) {
            const int row = (t >> 4) + 16 * i;
            const int col = (t & 15) * 4;
            // img side: sum 2 bf16 partials (verbatim r11)
            f32x4 iv = {0.f, 0.f, 0.f, 0.f};
            const unsigned short* pi = &hid0[(size_t)(b0 + row) * 1024 + hb + col];
            #pragma unroll
            for (int z = 0; z < 2; ++z) {
                u16x4 vz = *(const u16x4*)(pi + (size_t)z * pstride);
                iv[0] += bf2f(vz[0]); iv[1] += bf2f(vz[1]);
                iv[2] += bf2f(vz[2]); iv[3] += bf2f(vz[3]);
            }
            *(f32x4*)&imgs[row][col] = iv;

            // sem side: weighted gather of hid0_sem rows (attention applied here)
            f32x4 sv = {0.f, 0.f, 0.f, 0.f};
            if (c0 + row < CLS) {
                const int n = cnt_s[row];
                if (n <= CAP) {
                    for (int k = 0; k < n; ++k) {
                        const int c2 = hitc2[row][k];
                        const float wgt = hitw[row][k];
                        const unsigned short* ps2 = &hid0[(size_t)(256 + c2) * 1024 + hb + col];
                        f32x4 hv = {0.f, 0.f, 0.f, 0.f};
                        #pragma unroll
                        for (int z = 0; z < 2; ++z) {
                            u16x4 vz = *(const u16x4*)(ps2 + (size_t)z * pstride);
                            hv[0] += bf2f(vz[0]); hv[1] += bf2f(vz[1]);
                            hv[2] += bf2f(vz[2]); hv[3] += bf2f(vz[3]);
                        }
                        sv += wgt * hv;
                    }
                } else {
                    // exact slow path (never expected on this data)
                    const int r = c0 + row;
                    const float mr = mrow[row], ir = invrow[row];
                    for (int c2 = 0; c2 < CLS; ++c2) {
                        const float d = sim[(size_t)r * CLS + c2];
                        if (d > THRESH_) {
                            const float wgt = expf(T_TEMP_ * (d - mr)) * ir;
                            const unsigned short* ps2 = &hid0[(size_t)(256 + c2) * 1024 + hb + col];
                            f32x4 hv = {0.f, 0.f, 0.f, 0.f};
                            #pragma unroll
                            for (int z = 0; z < 2; ++z) {
                                u16x4 vz = *(const u16x4*)(ps2 + (size_t)z * pstride);
                                hv[0] += bf2f(vz[0]); hv[1] += bf2f(vz[1]);
                                hv[2] += bf2f(vz[2]); hv[3] += bf2f(vz[3]);
                            }
                            sv += wgt * hv;
                        }
                    }
                }
                const f32x4 bb = *(const f32x4*)&sem_b[hb + col];
                sv += bb;
            }
            *(f32x4*)&sems[row][col] = sv;
        }
        __syncthreads();

        #pragma unroll
        for (int h4 = 0; h4 < 16; ++h4) {
            f32x4 ia[4], sa[4];
            #pragma unroll
            for (int i = 0; i < 4; ++i) ia[i] = *(f32x4*)&imgs[tb + 16 * i][h4 * 4];
            #pragma unroll
            for (int j = 0; j < 4; ++j) sa[j] = *(f32x4*)&sems[tc + 16 * j][h4 * 4];
            const f32x4 wv = *(const f32x4*)&fcs[hs * 64 + h4 * 4];
            #pragma unroll
            for (int e2 = 0; e2 < 2; ++e2) {
                const f32x2 w2 = {wv[2 * e2], wv[2 * e2 + 1]};
                f32x2 ia2[4], sa2[4];
                #pragma unroll
                for (int i = 0; i < 4; ++i) ia2[i] = (f32x2){ia[i][2 * e2], ia[i][2 * e2 + 1]};
                #pragma unroll
                for (int j = 0; j < 4; ++j) sa2[j] = (f32x2){sa[j][2 * e2], sa[j][2 * e2 + 1]};
                #pragma unroll
                for (int i = 0; i < 4; ++i)
                    #pragma unroll
                    for (int j = 0; j < 4; ++j) {
                        f32x2 s2 = ia2[i] + sa2[j];
                        s2 = __builtin_elementwise_max(s2, (f32x2){0.f, 0.f});
                        acc2[i][j] += s2 * w2;
                    }
            }
        }
        __syncthreads();
    }

    const int nh = blockIdx.z;
    #pragma unroll
    for (int i = 0; i < 4; ++i) {
        const int b = b0 + tb + 16 * i;
        #pragma unroll
        for (int j = 0; j < 4; ++j) {
            const int cc = c0 + tc + 16 * j;
            if (cc < CLS)
                outpart[((size_t)nh * BATCH + b) * CLS + cc] = acc2[i][j][0] + acc2[i][j][1];
        }
    }
}

// =============== KE: finalize (r11-verified, verbatim) ===============
__global__ __launch_bounds__(256) void finalize_kernel(
    const float* __restrict__ partial, const float* __restrict__ fc_b,
    float* __restrict__ out)
{
    const int idx = blockIdx.x * 256 + threadIdx.x;
    if (idx >= BATCH * CLS) return;
    float s = fc_b[0];
    #pragma unroll
    for (int nh = 0; nh < 8; ++nh)
        s += partial[(size_t)nh * (BATCH * CLS) + idx];
    out[idx] = s;
}

extern "C" void kernel_launch(void* const* d_in, const int* in_sizes, int n_in,
                              void* d_out, int out_size, void* d_ws, size_t ws_size,
                              hipStream_t stream)
{
    const float* imgf  = (const float*)d_in[0];
    const float* attrs = (const float*)d_in[1];
    const float* attg  = (const float*)d_in[3];
    const float* imgw  = (const float*)d_in[4];
    const float* semw  = (const float*)d_in[5];
    const float* semb  = (const float*)d_in[6];
    const float* fcw   = (const float*)d_in[7];
    const float* fcb   = (const float*)d_in[8];
    float* out = (float*)d_out;

    char* ws = (char*)d_ws;
    size_t off = 0;
    auto alloc = [&](size_t b) { size_t o = off; off = (off + b + 255) & ~(size_t)255; return o; };
    float* gpart          = (float*)(ws + alloc((size_t)8 * 512 * 256 * 4));    // 4.19 MB
    unsigned short* gn_bf = (unsigned short*)(ws + alloc((size_t)500 * 256 * 2));
    float* sim            = (float*)(ws + alloc((size_t)CLS * CLS * 4));        // 1 MB
    unsigned short* hid0  = (unsigned short*)(ws + alloc((size_t)2 * 756 * 1024 * 2));
    float* outP           = (float*)(ws + alloc((size_t)8 * BATCH * CLS * 4));

    // KA: g partials (128 blocks) + hid0 partials (192 blocks) in one dispatch
    ka_kernel<<<320, 256, 0, stream>>>(attrs, attg, imgf, imgw, semw, gpart, hid0);
    // KB: reduce 8 partials + row-normalize -> gn bf16
    reduce_norm_kernel<<<CLS, 256, 0, stream>>>(gpart, gn_bf);
    // KC: sim = gn @ gn^T [500,500] f32
    sim_kernel<<<dim3(8, 4), 256, 0, stream>>>(gn_bf, sim);
    // KD: in-block softmax + sem gather + fused relu-reduction -> outP[8][256][500]
    fused_kernel<<<dim3(4, 8, 8), 256, 0, stream>>>(sim, hid0, semb, fcw, outP);
    // KE: finalize
    finalize_kernel<<<(BATCH * CLS + 255) / 256, 256, 0, stream>>>(outP, fcb, out);
}

// Round 13
// 67.006 us; speedup vs baseline: 1.2024x; 1.2024x over previous
//
#include <hip/hip_runtime.h>
#include <math.h>

#define BATCH 256
#define CLS 500
#define T_TEMP_ 10.0f
#define THRESH_ 0.86602540378443864676f
#define NEGV -9.0e15f

typedef __attribute__((ext_vector_type(8))) short short8;
typedef __attribute__((ext_vector_type(8))) unsigned short u16x8;
typedef __attribute__((ext_vector_type(4))) unsigned short u16x4;
typedef __attribute__((ext_vector_type(4))) float f32x4;
typedef __attribute__((ext_vector_type(2))) float f32x2;

static __device__ __forceinline__ unsigned short f2bf(float x) {
    unsigned int u = __builtin_bit_cast(unsigned int, x);
    u += 0x7fff + ((u >> 16) & 1);
    return (unsigned short)(u >> 16);
}
static __device__ __forceinline__ float bf2f(unsigned short v) {
    return __builtin_bit_cast(float, (unsigned int)v << 16);
}
static __device__ __forceinline__ float fel(const float4& v, int j) { return (&v.x)[j]; }
static __device__ __forceinline__ u16x8 pack8(const float4& a, const float4& b) {
    u16x8 o;
    o[0] = f2bf(a.x); o[1] = f2bf(a.y); o[2] = f2bf(a.z); o[3] = f2bf(a.w);
    o[4] = f2bf(b.x); o[5] = f2bf(b.y); o[6] = f2bf(b.z); o[7] = f2bf(b.w);
    return o;
}

// =============== K1: gpart[8][512][256] = split-K partials of g (r11-verified, verbatim) ===============
__global__ __launch_bounds__(256) void gpart_kernel(
    const float* __restrict__ attrs, const float* __restrict__ attg,
    float* __restrict__ gpart)
{
    __shared__ unsigned short As[64][40];
    __shared__ unsigned short Bs[128][40];
    const int t = threadIdx.x;
    const int bid = blockIdx.x;
    const int mt = bid >> 4, nt = (bid >> 3) & 1, split = bid & 7;
    const int n0 = nt * 128, ar0 = mt * 64, k0 = split * 128;

    const int w = t >> 6, lane = t & 63;
    const int wr = w >> 1, wc = w & 1;
    const int fr = lane & 15, kg = lane >> 4;
    const int as_row = t >> 2, as_kq = t & 3;
    const int bs_nc = (t & 31) * 4, bs_kr = t >> 5;

    f32x4 acc[2][4];
    #pragma unroll
    for (int i = 0; i < 2; ++i)
        #pragma unroll
        for (int j = 0; j < 4; ++j) acc[i][j] = (f32x4){0.f, 0.f, 0.f, 0.f};

    for (int kb = k0; kb < k0 + 128; kb += 32) {
        {
            const int gr = ar0 + as_row;
            float4 v0 = make_float4(0.f,0.f,0.f,0.f), v1 = v0;
            if (gr < CLS) {
                const float* ap = &attrs[(size_t)gr * 1024 + kb + as_kq * 8];
                v0 = *(const float4*)ap; v1 = *(const float4*)(ap + 4);
            }
            *(u16x8*)&As[as_row][as_kq * 8] = pack8(v0, v1);
        }
        {
            const float* bp = &attg[(size_t)(kb + bs_kr * 4) * 256 + n0 + bs_nc];
            float4 r0 = *(const float4*)(bp);
            float4 r1 = *(const float4*)(bp + 256);
            float4 r2 = *(const float4*)(bp + 512);
            float4 r3 = *(const float4*)(bp + 768);
            #pragma unroll
            for (int j = 0; j < 4; ++j) {
                unsigned int lo = (unsigned int)f2bf(fel(r0, j)) | ((unsigned int)f2bf(fel(r1, j)) << 16);
                unsigned int hi = (unsigned int)f2bf(fel(r2, j)) | ((unsigned int)f2bf(fel(r3, j)) << 16);
                uint2 u2; u2.x = lo; u2.y = hi;
                *(uint2*)&Bs[bs_nc + j][bs_kr * 4] = u2;
            }
        }
        __syncthreads();
        short8 af[2], bfr[4];
        #pragma unroll
        for (int i = 0; i < 2; ++i) af[i] = *(short8*)&As[wr * 32 + i * 16 + fr][kg * 8];
        #pragma unroll
        for (int j = 0; j < 4; ++j) bfr[j] = *(short8*)&Bs[wc * 64 + j * 16 + fr][kg * 8];
        #pragma unroll
        for (int i = 0; i < 2; ++i)
            #pragma unroll
            for (int j = 0; j < 4; ++j)
                acc[i][j] = __builtin_amdgcn_mfma_f32_16x16x32_bf16(af[i], bfr[j], acc[i][j], 0, 0, 0);
        __syncthreads();
    }

    float* Gp = gpart + (size_t)split * (512 * 256);
    const int orow0 = ar0 + wr * 32, ocol0 = n0 + wc * 64;
    #pragma unroll
    for (int i = 0; i < 2; ++i) {
        const int r0 = orow0 + i * 16 + kg * 4;
        #pragma unroll
        for (int j = 0; j < 4; ++j) {
            const int cc = ocol0 + j * 16 + fr;
            #pragma unroll
            for (int r = 0; r < 4; ++r)
                Gp[(size_t)(r0 + r) * 256 + cc] = acc[i][j][r];
        }
    }
}

// =============== K2: reduce 8 partials + row-normalize -> gn bf16 (r11-verified, verbatim) ===============
__global__ __launch_bounds__(256) void reduce_norm_kernel(
    const float* __restrict__ part, unsigned short* __restrict__ gn_bf)
{
    const int c = blockIdx.x, t = threadIdx.x;
    float v = 0.f;
    #pragma unroll
    for (int z = 0; z < 8; ++z) v += part[(size_t)z * (512 * 256) + c * 256 + t];
    float ss = v * v;
    #pragma unroll
    for (int off = 32; off >= 1; off >>= 1) ss += __shfl_down(ss, off);
    __shared__ float red[4];
    const int wave = t >> 6, lane = t & 63;
    if (lane == 0) red[wave] = ss;
    __syncthreads();
    const float tot = red[0] + red[1] + red[2] + red[3];
    const float rn  = 1.f / sqrtf(tot);
    gn_bf[c * 256 + t] = f2bf(v * rn);
}

// =============== K3: sim = gn @ gn^T (r11-verified mfma_gemm_bf, verbatim) ===============
__global__ __launch_bounds__(256) void mfma_gemm_bf(
    const unsigned short* __restrict__ A1, int alim1,
    const unsigned short* __restrict__ A2, int a2t0, int alim2,
    const unsigned short* __restrict__ B1, const unsigned short* __restrict__ B2,
    float* __restrict__ C, unsigned short* __restrict__ Cbf,
    int M, int N, int K, int klen)
{
    __shared__ unsigned short As[64][40];
    __shared__ unsigned short Bs[128][40];

    const int t  = threadIdx.x;
    const int bx = blockIdx.x;
    const int n0 = blockIdx.y * 128;
    const int k0 = blockIdx.z * klen;

    const unsigned short* A; const unsigned short* B; int ar0, alim;
    if (bx < a2t0) { A = A1; B = B1; ar0 = bx * 64;          alim = alim1; }
    else           { A = A2; B = B2; ar0 = (bx - a2t0) * 64; alim = alim2; }

    const int w = t >> 6, lane = t & 63;
    const int wr = w >> 1, wc = w & 1;
    const int fr = lane & 15, kg = lane >> 4;

    const int a_row = t >> 2, a_k = (t & 3) * 8;
    const int b_row = t >> 1, b_k = (t & 1) * 16;
    const int gra = ar0 + a_row;
    const int grb = n0 + b_row;
    const bool va = gra < alim;
    const bool vb = grb < N;
    const size_t abase = (size_t)gra * K + a_k;
    const size_t bbase = (size_t)grb * K + b_k;

    u16x8 zz = {0,0,0,0,0,0,0,0};
    u16x8 pa = zz, pb0 = zz, pb1 = zz;
    if (va) pa = *(const u16x8*)&A[abase + k0];
    if (vb) { pb0 = *(const u16x8*)&B[bbase + k0]; pb1 = *(const u16x8*)&B[bbase + k0 + 8]; }

    f32x4 acc[2][4];
    #pragma unroll
    for (int i = 0; i < 2; ++i)
        #pragma unroll
        for (int j = 0; j < 4; ++j) acc[i][j] = (f32x4){0.f, 0.f, 0.f, 0.f};

    for (int kb = k0; kb < k0 + klen; kb += 32) {
        *(u16x8*)&As[a_row][a_k] = pa;
        *(u16x8*)&Bs[b_row][b_k] = pb0;
        *(u16x8*)&Bs[b_row][b_k + 8] = pb1;
        __syncthreads();

        const int kn = kb + 32;
        if (kn < k0 + klen) {
            if (va) pa = *(const u16x8*)&A[abase + kn];
            if (vb) { pb0 = *(const u16x8*)&B[bbase + kn]; pb1 = *(const u16x8*)&B[bbase + kn + 8]; }
        }

        short8 af[2], bfr[4];
        #pragma unroll
        for (int i = 0; i < 2; ++i) af[i] = *(short8*)&As[wr * 32 + i * 16 + fr][kg * 8];
        #pragma unroll
        for (int j = 0; j < 4; ++j) bfr[j] = *(short8*)&Bs[wc * 64 + j * 16 + fr][kg * 8];
        #pragma unroll
        for (int i = 0; i < 2; ++i)
            #pragma unroll
            for (int j = 0; j < 4; ++j)
                acc[i][j] = __builtin_amdgcn_mfma_f32_16x16x32_bf16(af[i], bfr[j], acc[i][j], 0, 0, 0);
        __syncthreads();
    }

    const int orow0 = bx * 64 + wr * 32, ocol0 = n0 + wc * 64;
    if (Cbf) {
        unsigned short* Cw = Cbf + (size_t)blockIdx.z * M * N;
        #pragma unroll
        for (int i = 0; i < 2; ++i) {
            const int r0 = orow0 + i * 16 + kg * 4;
            #pragma unroll
            for (int j = 0; j < 4; ++j) {
                const int cc = ocol0 + j * 16 + fr;
                if (cc >= N) continue;
                #pragma unroll
                for (int r = 0; r < 4; ++r) {
                    const int rr = r0 + r;
                    if (rr < M) Cw[(size_t)rr * N + cc] = f2bf(acc[i][j][r]);
                }
            }
        }
    } else {
        float* Cw = C + (gridDim.z > 1 ? (size_t)blockIdx.z * M * N : 0);
        #pragma unroll
        for (int i = 0; i < 2; ++i) {
            const int r0 = orow0 + i * 16 + kg * 4;
            #pragma unroll
            for (int j = 0; j < 4; ++j) {
                const int cc = ocol0 + j * 16 + fr;
                if (cc >= N) continue;
                #pragma unroll
                for (int r = 0; r < 4; ++r) {
                    const int rr = r0 + r;
                    if (rr < M) Cw[(size_t)rr * N + cc] = acc[i][j][r];
                }
            }
        }
    }
}

// =============== K4: masked softmax + sparse attention (r11-verified, verbatim) ===============
__global__ __launch_bounds__(256) void softmax_att_kernel(
    const float* __restrict__ sim, const float* __restrict__ attrs,
    unsigned short* __restrict__ att_outs)
{
    const int c = blockIdx.x, t = threadIdx.x;
    __shared__ float p_s[512];
    __shared__ float redm[4];
    __shared__ float reds[4];

    const float d0 = sim[(size_t)c * CLS + t];
    const float d1 = (t + 256 < CLS) ? sim[(size_t)c * CLS + t + 256] : NEGV;

    float vmax = fmaxf((d0 > THRESH_) ? d0 : NEGV, (d1 > THRESH_) ? d1 : NEGV);
    #pragma unroll
    for (int off = 32; off >= 1; off >>= 1) vmax = fmaxf(vmax, __shfl_down(vmax, off));
    const int wave = t >> 6, lane = t & 63;
    if (lane == 0) redm[wave] = vmax;
    __syncthreads();
    const float m = fmaxf(fmaxf(redm[0], redm[1]), fmaxf(redm[2], redm[3]));

    const float p0 = (d0 > THRESH_) ? expf(T_TEMP_ * (d0 - m)) : 0.f;
    const float p1 = (d1 > THRESH_) ? expf(T_TEMP_ * (d1 - m)) : 0.f;
    p_s[t] = p0;
    p_s[t + 256] = p1;
    float vsum = p0 + p1;
    #pragma unroll
    for (int off = 32; off >= 1; off >>= 1) vsum += __shfl_down(vsum, off);
    if (lane == 0) reds[wave] = vsum;
    __syncthreads();
    const float inv = 1.f / (reds[0] + reds[1] + reds[2] + reds[3]);

    float acc[4] = {0.f, 0.f, 0.f, 0.f};
    for (int base = 0; base < 512; base += 64) {
        const float pv_l = p_s[base + lane];
        unsigned long long mask = __ballot(pv_l > 0.f);
        while (mask) {
            const int l = __ffsll((long long)mask) - 1;
            mask &= mask - 1;
            const int c2 = base + l;
            const float pv = p_s[c2];
            const float* ar = &attrs[(size_t)c2 * 1024 + t];
            #pragma unroll
            for (int j = 0; j < 4; ++j) acc[j] += pv * ar[256 * j];
        }
    }
    #pragma unroll
    for (int j = 0; j < 4; ++j)
        att_outs[(size_t)c * 1024 + t + 256 * j] = f2bf(acc[j] * inv);
}

// =============== K5: hid partials (r11-verified body; split-K 4, klen=256) ===============
__global__ __launch_bounds__(256) void hid_kernel(
    const float* __restrict__ imgf, const unsigned short* __restrict__ atto_bf,
    const float* __restrict__ imgw, const float* __restrict__ semw,
    unsigned short* __restrict__ hidP)
{
    __shared__ unsigned short As[64][40];
    __shared__ unsigned short Bs[128][40];
    const int t = threadIdx.x;
    const int mt = blockIdx.x, nt = blockIdx.y, split = blockIdx.z;
    const int n0 = nt * 128, k0 = split * 256;
    const bool img_side = (mt < 4);
    const int ar0 = img_side ? mt * 64 : (mt - 4) * 64;
    const int alim = img_side ? 256 : 500;
    const float* Bf = img_side ? imgw : semw;

    const int w = t >> 6, lane = t & 63;
    const int wr = w >> 1, wc = w & 1;
    const int fr = lane & 15, kg = lane >> 4;
    const int as_row = t >> 2, as_kq = t & 3;
    const int bs_nc = (t & 31) * 4, bs_kr = t >> 5;

    f32x4 acc[2][4];
    #pragma unroll
    for (int i = 0; i < 2; ++i)
        #pragma unroll
        for (int j = 0; j < 4; ++j) acc[i][j] = (f32x4){0.f, 0.f, 0.f, 0.f};

    for (int kb = k0; kb < k0 + 256; kb += 32) {
        {
            const int gr = ar0 + as_row;
            if (img_side) {
                float4 v0 = make_float4(0.f,0.f,0.f,0.f), v1 = v0;
                if (gr < alim) {
                    const float* ap = &imgf[(size_t)gr * 1024 + kb + as_kq * 8];
                    v0 = *(const float4*)ap; v1 = *(const float4*)(ap + 4);
                }
                *(u16x8*)&As[as_row][as_kq * 8] = pack8(v0, v1);
            } else {
                u16x8 pa = {0,0,0,0,0,0,0,0};
                if (gr < alim) pa = *(const u16x8*)&atto_bf[(size_t)gr * 1024 + kb + as_kq * 8];
                *(u16x8*)&As[as_row][as_kq * 8] = pa;
            }
        }
        {
            const float* bp = &Bf[(size_t)(kb + bs_kr * 4) * 1024 + n0 + bs_nc];
            float4 r0 = *(const float4*)(bp);
            float4 r1 = *(const float4*)(bp + 1024);
            float4 r2 = *(const float4*)(bp + 2048);
            float4 r3 = *(const float4*)(bp + 3072);
            #pragma unroll
            for (int j = 0; j < 4; ++j) {
                unsigned int lo = (unsigned int)f2bf(fel(r0, j)) | ((unsigned int)f2bf(fel(r1, j)) << 16);
                unsigned int hi = (unsigned int)f2bf(fel(r2, j)) | ((unsigned int)f2bf(fel(r3, j)) << 16);
                uint2 u2; u2.x = lo; u2.y = hi;
                *(uint2*)&Bs[bs_nc + j][bs_kr * 4] = u2;
            }
        }
        __syncthreads();
        short8 af[2], bfr[4];
        #pragma unroll
        for (int i = 0; i < 2; ++i) af[i] = *(short8*)&As[wr * 32 + i * 16 + fr][kg * 8];
        #pragma unroll
        for (int j = 0; j < 4; ++j) bfr[j] = *(short8*)&Bs[wc * 64 + j * 16 + fr][kg * 8];
        #pragma unroll
        for (int i = 0; i < 2; ++i)
            #pragma unroll
            for (int j = 0; j < 4; ++j)
                acc[i][j] = __builtin_amdgcn_mfma_f32_16x16x32_bf16(af[i], bfr[j], acc[i][j], 0, 0, 0);
        __syncthreads();
    }

    unsigned short* Cw = hidP + (size_t)split * (756 * 1024);
    const int orow0 = mt * 64 + wr * 32, ocol0 = n0 + wc * 64;
    #pragma unroll
    for (int i = 0; i < 2; ++i) {
        const int r0 = orow0 + i * 16 + kg * 4;
        #pragma unroll
        for (int j = 0; j < 4; ++j) {
            const int cc = ocol0 + j * 16 + fr;
            #pragma unroll
            for (int r = 0; r < 4; ++r) {
                const int rr = r0 + r;
                if (rr < 756) Cw[(size_t)rr * 1024 + cc] = f2bf(acc[i][j][r]);
            }
        }
    }
}

// =============== K6: fused relu-reduction, re-gridded for occupancy ===============
// grid (4,8,32): 64x64 output tile, h_per=32, 1024 blocks (~4/CU -> 4 waves/SIMD).
// Sums 4 bf16 hid partials inline; math identical to r11 body.
__global__ __launch_bounds__(256) void fused_out_partial(
    const unsigned short* __restrict__ part, const float* __restrict__ sem_b,
    const float* __restrict__ fc_w, float* __restrict__ outpart)
{
    __shared__ float imgs[64][36];   // 32 + 4 pad
    __shared__ float sems[64][36];
    __shared__ float fcs[32];

    const size_t pstride = (size_t)756 * 1024;
    const int t  = threadIdx.x;
    const int tb = t >> 4, tc = t & 15;
    const int b0 = blockIdx.x * 64, c0 = blockIdx.y * 64;
    const int h0 = blockIdx.z * 32;

    if (t < 8) *(float4*)&fcs[t * 4] = *(const float4*)&fc_w[h0 + t * 4];

    // staging: 64 rows x 4 col-octets (u16x8 per split)
    {
        const int row = t >> 2, col = (t & 3) * 8;
        f32x4 iv0 = {0.f,0.f,0.f,0.f}, iv1 = iv0;
        const unsigned short* pi = &part[(size_t)(b0 + row) * 1024 + h0 + col];
        #pragma unroll
        for (int z = 0; z < 4; ++z) {
            u16x8 vz = *(const u16x8*)(pi + (size_t)z * pstride);
            iv0[0] += bf2f(vz[0]); iv0[1] += bf2f(vz[1]);
            iv0[2] += bf2f(vz[2]); iv0[3] += bf2f(vz[3]);
            iv1[0] += bf2f(vz[4]); iv1[1] += bf2f(vz[5]);
            iv1[2] += bf2f(vz[6]); iv1[3] += bf2f(vz[7]);
        }
        *(f32x4*)&imgs[row][col]     = iv0;
        *(f32x4*)&imgs[row][col + 4] = iv1;

        f32x4 sv0 = {0.f,0.f,0.f,0.f}, sv1 = sv0;
        if (c0 + row < CLS) {
            const unsigned short* ps2 = &part[(size_t)(256 + c0 + row) * 1024 + h0 + col];
            #pragma unroll
            for (int z = 0; z < 4; ++z) {
                u16x8 vz = *(const u16x8*)(ps2 + (size_t)z * pstride);
                sv0[0] += bf2f(vz[0]); sv0[1] += bf2f(vz[1]);
                sv0[2] += bf2f(vz[2]); sv0[3] += bf2f(vz[3]);
                sv1[0] += bf2f(vz[4]); sv1[1] += bf2f(vz[5]);
                sv1[2] += bf2f(vz[6]); sv1[3] += bf2f(vz[7]);
            }
            sv0 += *(const f32x4*)&sem_b[h0 + col];
            sv1 += *(const f32x4*)&sem_b[h0 + col + 4];
        }
        *(f32x4*)&sems[row][col]     = sv0;
        *(f32x4*)&sems[row][col + 4] = sv1;
    }
    __syncthreads();

    f32x2 acc2[4][4];
    #pragma unroll
    for (int i = 0; i < 4; ++i)
        #pragma unroll
        for (int j = 0; j < 4; ++j) acc2[i][j] = (f32x2){0.f, 0.f};

    #pragma unroll
    for (int h4 = 0; h4 < 8; ++h4) {
        f32x4 ia[4], sa[4];
        #pragma unroll
        for (int i = 0; i < 4; ++i) ia[i] = *(f32x4*)&imgs[tb + 16 * i][h4 * 4];
        #pragma unroll
        for (int j = 0; j < 4; ++j) sa[j] = *(f32x4*)&sems[tc + 16 * j][h4 * 4];
        const f32x4 wv = *(const f32x4*)&fcs[h4 * 4];
        #pragma unroll
        for (int e2 = 0; e2 < 2; ++e2) {
            const f32x2 w2 = {wv[2 * e2], wv[2 * e2 + 1]};
            f32x2 ia2[4], sa2[4];
            #pragma unroll
            for (int i = 0; i < 4; ++i) ia2[i] = (f32x2){ia[i][2 * e2], ia[i][2 * e2 + 1]};
            #pragma unroll
            for (int j = 0; j < 4; ++j) sa2[j] = (f32x2){sa[j][2 * e2], sa[j][2 * e2 + 1]};
            #pragma unroll
            for (int i = 0; i < 4; ++i)
                #pragma unroll
                for (int j = 0; j < 4; ++j) {
                    f32x2 s = ia2[i] + sa2[j];
                    s = __builtin_elementwise_max(s, (f32x2){0.f, 0.f});
                    acc2[i][j] += s * w2;
                }
        }
    }

    const int nh = blockIdx.z;
    #pragma unroll
    for (int i = 0; i < 4; ++i) {
        const int b = b0 + tb + 16 * i;
        #pragma unroll
        for (int j = 0; j < 4; ++j) {
            const int cc = c0 + tc + 16 * j;
            if (cc < CLS)
                outpart[((size_t)nh * BATCH + b) * CLS + cc] = acc2[i][j][0] + acc2[i][j][1];
        }
    }
}

// =============== K7: finalize (32 partials) ===============
__global__ __launch_bounds__(256) void finalize_kernel(
    const float* __restrict__ partial, const float* __restrict__ fc_b,
    float* __restrict__ out)
{
    const int idx = blockIdx.x * 256 + threadIdx.x;
    if (idx >= BATCH * CLS) return;
    float s = fc_b[0];
    #pragma unroll
    for (int nh = 0; nh < 32; ++nh)
        s += partial[(size_t)nh * (BATCH * CLS) + idx];
    out[idx] = s;
}

extern "C" void kernel_launch(void* const* d_in, const int* in_sizes, int n_in,
                              void* d_out, int out_size, void* d_ws, size_t ws_size,
                              hipStream_t stream)
{
    const float* imgf  = (const float*)d_in[0];
    const float* attrs = (const float*)d_in[1];
    const float* attg  = (const float*)d_in[3];
    const float* imgw  = (const float*)d_in[4];
    const float* semw  = (const float*)d_in[5];
    const float* semb  = (const float*)d_in[6];
    const float* fcw   = (const float*)d_in[7];
    const float* fcb   = (const float*)d_in[8];
    float* out = (float*)d_out;

    char* ws = (char*)d_ws;
    size_t off = 0;
    auto alloc = [&](size_t b) { size_t o = off; off = (off + b + 255) & ~(size_t)255; return o; };
    float* gpart          = (float*)(ws + alloc((size_t)8 * 512 * 256 * 4));     // 4.19 MB
    unsigned short* gn_bf = (unsigned short*)(ws + alloc((size_t)500 * 256 * 2));
    float* sim            = (float*)(ws + alloc((size_t)CLS * CLS * 4));         // 1 MB
    unsigned short* atto  = (unsigned short*)(ws + alloc((size_t)500 * 1024 * 2));
    unsigned short* hidP  = (unsigned short*)(ws + alloc((size_t)4 * 756 * 1024 * 2));  // 6.2 MB
    float* outP           = (float*)(ws + alloc((size_t)32 * BATCH * CLS * 4));  // 16.4 MB

    // K1: g split-K partials (inline convert)
    gpart_kernel<<<128, 256, 0, stream>>>(attrs, attg, gpart);
    // K2: reduce 8 partials + row-normalize -> gn bf16
    reduce_norm_kernel<<<CLS, 256, 0, stream>>>(gpart, gn_bf);
    // K3: sim = gn @ gn^T [500,500] f32
    mfma_gemm_bf<<<dim3(8, 4, 1), 256, 0, stream>>>(
        gn_bf, 500, gn_bf, 1000, 500, gn_bf, gn_bf,
        sim, nullptr, 500, 500, 256, 256);
    // K4: masked softmax + sparse accumulate -> atto bf16
    softmax_att_kernel<<<CLS, 256, 0, stream>>>(sim, attrs, atto);
    // K5: hid partials [4][756][1024] bf16 (inline convert), split-K 4
    hid_kernel<<<dim3(12, 8, 4), 256, 0, stream>>>(imgf, atto, imgw, semw, hidP);
    // K6: fused relu-reduction -> outP[32][256][500], 1024 blocks
    fused_out_partial<<<dim3(4, 8, 32), 256, 0, stream>>>(hidP, semb, fcw, outP);
    // K7: finalize (32 partials)
    finalize_kernel<<<(BATCH * CLS + 255) / 256, 256, 0, stream>>>(outP, fcb, out);
}

// Round 14
// 64.443 us; speedup vs baseline: 1.2502x; 1.0398x over previous
//
#include <hip/hip_runtime.h>
#include <math.h>

#define BATCH 256
#define CLS 500
#define T_TEMP_ 10.0f
#define THRESH_ 0.86602540378443864676f
#define NEGV -9.0e15f

typedef __attribute__((ext_vector_type(8))) short short8;
typedef __attribute__((ext_vector_type(8))) unsigned short u16x8;
typedef __attribute__((ext_vector_type(4))) unsigned short u16x4;
typedef __attribute__((ext_vector_type(4))) float f32x4;
typedef __attribute__((ext_vector_type(2))) float f32x2;

static __device__ __forceinline__ unsigned short f2bf(float x) {
    unsigned int u = __builtin_bit_cast(unsigned int, x);
    u += 0x7fff + ((u >> 16) & 1);
    return (unsigned short)(u >> 16);
}
static __device__ __forceinline__ float bf2f(unsigned short v) {
    return __builtin_bit_cast(float, (unsigned int)v << 16);
}
static __device__ __forceinline__ float fel(const float4& v, int j) { return (&v.x)[j]; }
static __device__ __forceinline__ u16x8 pack8(const float4& a, const float4& b) {
    u16x8 o;
    o[0] = f2bf(a.x); o[1] = f2bf(a.y); o[2] = f2bf(a.z); o[3] = f2bf(a.w);
    o[4] = f2bf(b.x); o[5] = f2bf(b.y); o[6] = f2bf(b.z); o[7] = f2bf(b.w);
    return o;
}

// =============== N1: mega-GEMM — 3 independent families, one dispatch ===============
// bid [0,128):   G: gpart[8][512][256] f32 = split-K8 partials of attrs@attg (r13 body)
// bid [128,192): I: imgP[2][256][1024] bf16 = split-K2 partials of imgf@imgw
// bid [192,320): S: asemP[2][512][1024] bf16 = split-K2 partials of attrs@semw
__global__ __launch_bounds__(256) void mega_gemm(
    const float* __restrict__ attrs, const float* __restrict__ attg,
    const float* __restrict__ imgf, const float* __restrict__ imgw,
    const float* __restrict__ semw,
    float* __restrict__ gpart, unsigned short* __restrict__ imgP,
    unsigned short* __restrict__ asemP)
{
    __shared__ unsigned short As[64][40];
    __shared__ unsigned short Bs[128][40];
    const int t = threadIdx.x;
    const int bid = blockIdx.x;

    const int w = t >> 6, lane = t & 63;
    const int wr = w >> 1, wc = w & 1;
    const int fr = lane & 15, kg = lane >> 4;
    const int as_row = t >> 2, as_kq = t & 3;
    const int bs_nc = (t & 31) * 4, bs_kr = t >> 5;

    const float* A; const float* Bf;
    int ar0, alim, n0, k0, klen, bstride, split;
    if (bid < 128) {
        const int mt = bid >> 4, nt = (bid >> 3) & 1; split = bid & 7;
        A = attrs; alim = CLS; ar0 = mt * 64;
        Bf = attg; bstride = 256; n0 = nt * 128;
        k0 = split * 128; klen = 128;
    } else if (bid < 192) {
        const int idx = bid - 128; split = idx & 1;
        const int nt = (idx >> 1) & 7, mt = idx >> 4;
        A = imgf; alim = 256; ar0 = mt * 64;
        Bf = imgw; bstride = 1024; n0 = nt * 128;
        k0 = split * 512; klen = 512;
    } else {
        const int idx = bid - 192; split = idx & 1;
        const int nt = (idx >> 1) & 7, mt = idx >> 4;
        A = attrs; alim = CLS; ar0 = mt * 64;
        Bf = semw; bstride = 1024; n0 = nt * 128;
        k0 = split * 512; klen = 512;
    }

    f32x4 acc[2][4];
    #pragma unroll
    for (int i = 0; i < 2; ++i)
        #pragma unroll
        for (int j = 0; j < 4; ++j) acc[i][j] = (f32x4){0.f, 0.f, 0.f, 0.f};

    for (int kb = k0; kb < k0 + klen; kb += 32) {
        {   // A stage: f32 -> bf16 (r13-verified pattern)
            const int gr = ar0 + as_row;
            float4 v0 = make_float4(0.f,0.f,0.f,0.f), v1 = v0;
            if (gr < alim) {
                const float* ap = &A[(size_t)gr * 1024 + kb + as_kq * 8];
                v0 = *(const float4*)ap; v1 = *(const float4*)(ap + 4);
            }
            *(u16x8*)&As[as_row][as_kq * 8] = pack8(v0, v1);
        }
        {   // B stage: f32 [K][bstride] row-major -> Bs[n][k] (r13-verified pattern)
            const float* bp = &Bf[(size_t)(kb + bs_kr * 4) * bstride + n0 + bs_nc];
            float4 r0 = *(const float4*)(bp);
            float4 r1 = *(const float4*)(bp + bstride);
            float4 r2 = *(const float4*)(bp + 2 * bstride);
            float4 r3 = *(const float4*)(bp + 3 * bstride);
            #pragma unroll
            for (int j = 0; j < 4; ++j) {
                unsigned int lo = (unsigned int)f2bf(fel(r0, j)) | ((unsigned int)f2bf(fel(r1, j)) << 16);
                unsigned int hi = (unsigned int)f2bf(fel(r2, j)) | ((unsigned int)f2bf(fel(r3, j)) << 16);
                uint2 u2; u2.x = lo; u2.y = hi;
                *(uint2*)&Bs[bs_nc + j][bs_kr * 4] = u2;
            }
        }
        __syncthreads();
        short8 af[2], bfr[4];
        #pragma unroll
        for (int i = 0; i < 2; ++i) af[i] = *(short8*)&As[wr * 32 + i * 16 + fr][kg * 8];
        #pragma unroll
        for (int j = 0; j < 4; ++j) bfr[j] = *(short8*)&Bs[wc * 64 + j * 16 + fr][kg * 8];
        #pragma unroll
        for (int i = 0; i < 2; ++i)
            #pragma unroll
            for (int j = 0; j < 4; ++j)
                acc[i][j] = __builtin_amdgcn_mfma_f32_16x16x32_bf16(af[i], bfr[j], acc[i][j], 0, 0, 0);
        __syncthreads();
    }

    const int orow0 = ar0 + wr * 32, ocol0 = n0 + wc * 64;
    if (bid < 128) {
        float* Gp = gpart + (size_t)split * (512 * 256);
        #pragma unroll
        for (int i = 0; i < 2; ++i) {
            const int r0 = orow0 + i * 16 + kg * 4;
            #pragma unroll
            for (int j = 0; j < 4; ++j) {
                const int cc = ocol0 + j * 16 + fr;
                #pragma unroll
                for (int r = 0; r < 4; ++r)
                    Gp[(size_t)(r0 + r) * 256 + cc] = acc[i][j][r];
            }
        }
    } else {
        unsigned short* Cw = (bid < 192)
            ? imgP  + (size_t)split * (256 * 1024)
            : asemP + (size_t)split * (512 * 1024);
        #pragma unroll
        for (int i = 0; i < 2; ++i) {
            const int r0 = orow0 + i * 16 + kg * 4;
            #pragma unroll
            for (int j = 0; j < 4; ++j) {
                const int cc = ocol0 + j * 16 + fr;
                #pragma unroll
                for (int r = 0; r < 4; ++r)
                    Cw[(size_t)(r0 + r) * 1024 + cc] = f2bf(acc[i][j][r]);
            }
        }
    }
}

// =============== N2: reduce 8 partials + row-normalize -> gn bf16 (r13-verified, verbatim) ===============
__global__ __launch_bounds__(256) void reduce_norm_kernel(
    const float* __restrict__ part, unsigned short* __restrict__ gn_bf)
{
    const int c = blockIdx.x, t = threadIdx.x;
    float v = 0.f;
    #pragma unroll
    for (int z = 0; z < 8; ++z) v += part[(size_t)z * (512 * 256) + c * 256 + t];
    float ss = v * v;
    #pragma unroll
    for (int off = 32; off >= 1; off >>= 1) ss += __shfl_down(ss, off);
    __shared__ float red[4];
    const int wave = t >> 6, lane = t & 63;
    if (lane == 0) red[wave] = ss;
    __syncthreads();
    const float tot = red[0] + red[1] + red[2] + red[3];
    const float rn  = 1.f / sqrtf(tot);
    gn_bf[c * 256 + t] = f2bf(v * rn);
}

// =============== N3: sim = gn @ gn^T (r13-verified mfma_gemm_bf, fixed-shape) ===============
__global__ __launch_bounds__(256) void sim_kernel(
    const unsigned short* __restrict__ gn, float* __restrict__ S)
{
    __shared__ unsigned short As[64][40];
    __shared__ unsigned short Bs[128][40];
    const int t  = threadIdx.x;
    const int ar0 = blockIdx.x * 64;
    const int n0  = blockIdx.y * 128;

    const int w = t >> 6, lane = t & 63;
    const int wr = w >> 1, wc = w & 1;
    const int fr = lane & 15, kg = lane >> 4;
    const int a_row = t >> 2, a_k = (t & 3) * 8;
    const int b_row = t >> 1, b_k = (t & 1) * 16;
    const int gra = ar0 + a_row;
    const int grb = n0 + b_row;
    const bool va = gra < CLS;
    const bool vb = grb < CLS;
    const size_t abase = (size_t)gra * 256 + a_k;
    const size_t bbase = (size_t)grb * 256 + b_k;

    u16x8 zz = {0,0,0,0,0,0,0,0};
    u16x8 pa = zz, pb0 = zz, pb1 = zz;
    if (va) pa = *(const u16x8*)&gn[abase];
    if (vb) { pb0 = *(const u16x8*)&gn[bbase]; pb1 = *(const u16x8*)&gn[bbase + 8]; }

    f32x4 acc[2][4];
    #pragma unroll
    for (int i = 0; i < 2; ++i)
        #pragma unroll
        for (int j = 0; j < 4; ++j) acc[i][j] = (f32x4){0.f, 0.f, 0.f, 0.f};

    for (int kb = 0; kb < 256; kb += 32) {
        *(u16x8*)&As[a_row][a_k] = pa;
        *(u16x8*)&Bs[b_row][b_k] = pb0;
        *(u16x8*)&Bs[b_row][b_k + 8] = pb1;
        __syncthreads();

        const int kn = kb + 32;
        if (kn < 256) {
            if (va) pa = *(const u16x8*)&gn[abase + kn];
            if (vb) { pb0 = *(const u16x8*)&gn[bbase + kn]; pb1 = *(const u16x8*)&gn[bbase + kn + 8]; }
        }

        short8 af[2], bfr[4];
        #pragma unroll
        for (int i = 0; i < 2; ++i) af[i] = *(short8*)&As[wr * 32 + i * 16 + fr][kg * 8];
        #pragma unroll
        for (int j = 0; j < 4; ++j) bfr[j] = *(short8*)&Bs[wc * 64 + j * 16 + fr][kg * 8];
        #pragma unroll
        for (int i = 0; i < 2; ++i)
            #pragma unroll
            for (int j = 0; j < 4; ++j)
                acc[i][j] = __builtin_amdgcn_mfma_f32_16x16x32_bf16(af[i], bfr[j], acc[i][j], 0, 0, 0);
        __syncthreads();
    }

    const int orow0 = ar0 + wr * 32, ocol0 = n0 + wc * 64;
    #pragma unroll
    for (int i = 0; i < 2; ++i) {
        const int r0 = orow0 + i * 16 + kg * 4;
        #pragma unroll
        for (int j = 0; j < 4; ++j) {
            const int cc = ocol0 + j * 16 + fr;
            if (cc >= CLS) continue;
            #pragma unroll
            for (int r = 0; r < 4; ++r) {
                const int rr = r0 + r;
                if (rr < CLS) S[(size_t)rr * CLS + cc] = acc[i][j][r];
            }
        }
    }
}

// =============== N4: masked softmax + gather from asem (+semb) -> sem_h bf16 ===============
// Weight computation verbatim from r13-verified softmax_att_kernel; gather target
// switched from attrs to asem partials (associativity: A@(attrs@semw)).
__global__ __launch_bounds__(256) void softmax_gather_kernel(
    const float* __restrict__ sim, const unsigned short* __restrict__ asemP,
    const float* __restrict__ semb, unsigned short* __restrict__ sem_h)
{
    const int c = blockIdx.x, t = threadIdx.x;
    __shared__ float p_s[512];
    __shared__ float redm[4];
    __shared__ float reds[4];

    const float d0 = sim[(size_t)c * CLS + t];
    const float d1 = (t + 256 < CLS) ? sim[(size_t)c * CLS + t + 256] : NEGV;

    float vmax = fmaxf((d0 > THRESH_) ? d0 : NEGV, (d1 > THRESH_) ? d1 : NEGV);
    #pragma unroll
    for (int off = 32; off >= 1; off >>= 1) vmax = fmaxf(vmax, __shfl_down(vmax, off));
    const int wave = t >> 6, lane = t & 63;
    if (lane == 0) redm[wave] = vmax;
    __syncthreads();
    const float m = fmaxf(fmaxf(redm[0], redm[1]), fmaxf(redm[2], redm[3]));

    const float p0 = (d0 > THRESH_) ? expf(T_TEMP_ * (d0 - m)) : 0.f;
    const float p1 = (d1 > THRESH_) ? expf(T_TEMP_ * (d1 - m)) : 0.f;
    p_s[t] = p0;
    p_s[t + 256] = p1;
    float vsum = p0 + p1;
    #pragma unroll
    for (int off = 32; off >= 1; off >>= 1) vsum += __shfl_down(vsum, off);
    if (lane == 0) reds[wave] = vsum;
    __syncthreads();
    const float inv = 1.f / (reds[0] + reds[1] + reds[2] + reds[3]);

    float acc[4] = {0.f, 0.f, 0.f, 0.f};
    for (int base = 0; base < 512; base += 64) {
        const float pv_l = p_s[base + lane];
        unsigned long long mask = __ballot(pv_l > 0.f);
        while (mask) {
            const int l = __ffsll((long long)mask) - 1;
            mask &= mask - 1;
            const int c2 = base + l;
            const float pv = p_s[c2];
            const unsigned short* a0 = &asemP[(size_t)c2 * 1024 + t];
            const unsigned short* a1 = a0 + (size_t)512 * 1024;
            #pragma unroll
            for (int j = 0; j < 4; ++j)
                acc[j] += pv * (bf2f(a0[256 * j]) + bf2f(a1[256 * j]));
        }
    }
    #pragma unroll
    for (int j = 0; j < 4; ++j)
        sem_h[(size_t)c * 1024 + t + 256 * j] =
            f2bf(acc[j] * inv + semb[t + 256 * j]);
}

// =============== N5: fused relu-reduction (r13-verified re-grid; img 2 partials, sem direct) ===============
// grid (4,8,32): 64x64 output tile, h_per=32, 1024 blocks.
__global__ __launch_bounds__(256) void fused_out_partial(
    const unsigned short* __restrict__ imgP, const unsigned short* __restrict__ sem_h,
    const float* __restrict__ fc_w, float* __restrict__ outpart)
{
    __shared__ float imgs[64][36];
    __shared__ float sems[64][36];
    __shared__ float fcs[32];

    const size_t istride = (size_t)256 * 1024;
    const int t  = threadIdx.x;
    const int tb = t >> 4, tc = t & 15;
    const int b0 = blockIdx.x * 64, c0 = blockIdx.y * 64;
    const int h0 = blockIdx.z * 32;

    if (t < 8) *(float4*)&fcs[t * 4] = *(const float4*)&fc_w[h0 + t * 4];

    {
        const int row = t >> 2, col = (t & 3) * 8;
        f32x4 iv0 = {0.f,0.f,0.f,0.f}, iv1 = iv0;
        const unsigned short* pi = &imgP[(size_t)(b0 + row) * 1024 + h0 + col];
        #pragma unroll
        for (int z = 0; z < 2; ++z) {
            u16x8 vz = *(const u16x8*)(pi + (size_t)z * istride);
            iv0[0] += bf2f(vz[0]); iv0[1] += bf2f(vz[1]);
            iv0[2] += bf2f(vz[2]); iv0[3] += bf2f(vz[3]);
            iv1[0] += bf2f(vz[4]); iv1[1] += bf2f(vz[5]);
            iv1[2] += bf2f(vz[6]); iv1[3] += bf2f(vz[7]);
        }
        *(f32x4*)&imgs[row][col]     = iv0;
        *(f32x4*)&imgs[row][col + 4] = iv1;

        f32x4 sv0 = {0.f,0.f,0.f,0.f}, sv1 = sv0;
        if (c0 + row < CLS) {
            u16x8 vz = *(const u16x8*)&sem_h[(size_t)(c0 + row) * 1024 + h0 + col];
            sv0[0] = bf2f(vz[0]); sv0[1] = bf2f(vz[1]);
            sv0[2] = bf2f(vz[2]); sv0[3] = bf2f(vz[3]);
            sv1[0] = bf2f(vz[4]); sv1[1] = bf2f(vz[5]);
            sv1[2] = bf2f(vz[6]); sv1[3] = bf2f(vz[7]);
        }
        *(f32x4*)&sems[row][col]     = sv0;
        *(f32x4*)&sems[row][col + 4] = sv1;
    }
    __syncthreads();

    f32x2 acc2[4][4];
    #pragma unroll
    for (int i = 0; i < 4; ++i)
        #pragma unroll
        for (int j = 0; j < 4; ++j) acc2[i][j] = (f32x2){0.f, 0.f};

    #pragma unroll
    for (int h4 = 0; h4 < 8; ++h4) {
        f32x4 ia[4], sa[4];
        #pragma unroll
        for (int i = 0; i < 4; ++i) ia[i] = *(f32x4*)&imgs[tb + 16 * i][h4 * 4];
        #pragma unroll
        for (int j = 0; j < 4; ++j) sa[j] = *(f32x4*)&sems[tc + 16 * j][h4 * 4];
        const f32x4 wv = *(const f32x4*)&fcs[h4 * 4];
        #pragma unroll
        for (int e2 = 0; e2 < 2; ++e2) {
            const f32x2 w2 = {wv[2 * e2], wv[2 * e2 + 1]};
            f32x2 ia2[4], sa2[4];
            #pragma unroll
            for (int i = 0; i < 4; ++i) ia2[i] = (f32x2){ia[i][2 * e2], ia[i][2 * e2 + 1]};
            #pragma unroll
            for (int j = 0; j < 4; ++j) sa2[j] = (f32x2){sa[j][2 * e2], sa[j][2 * e2 + 1]};
            #pragma unroll
            for (int i = 0; i < 4; ++i)
                #pragma unroll
                for (int j = 0; j < 4; ++j) {
                    f32x2 s = ia2[i] + sa2[j];
                    s = __builtin_elementwise_max(s, (f32x2){0.f, 0.f});
                    acc2[i][j] += s * w2;
                }
        }
    }

    const int nh = blockIdx.z;
    #pragma unroll
    for (int i = 0; i < 4; ++i) {
        const int b = b0 + tb + 16 * i;
        #pragma unroll
        for (int j = 0; j < 4; ++j) {
            const int cc = c0 + tc + 16 * j;
            if (cc < CLS)
                outpart[((size_t)nh * BATCH + b) * CLS + cc] = acc2[i][j][0] + acc2[i][j][1];
        }
    }
}

// =============== N6: finalize (32 partials, r13-verified verbatim) ===============
__global__ __launch_bounds__(256) void finalize_kernel(
    const float* __restrict__ partial, const float* __restrict__ fc_b,
    float* __restrict__ out)
{
    const int idx = blockIdx.x * 256 + threadIdx.x;
    if (idx >= BATCH * CLS) return;
    float s = fc_b[0];
    #pragma unroll
    for (int nh = 0; nh < 32; ++nh)
        s += partial[(size_t)nh * (BATCH * CLS) + idx];
    out[idx] = s;
}

extern "C" void kernel_launch(void* const* d_in, const int* in_sizes, int n_in,
                              void* d_out, int out_size, void* d_ws, size_t ws_size,
                              hipStream_t stream)
{
    const float* imgf  = (const float*)d_in[0];
    const float* attrs = (const float*)d_in[1];
    const float* attg  = (const float*)d_in[3];
    const float* imgw  = (const float*)d_in[4];
    const float* semw  = (const float*)d_in[5];
    const float* semb  = (const float*)d_in[6];
    const float* fcw   = (const float*)d_in[7];
    const float* fcb   = (const float*)d_in[8];
    float* out = (float*)d_out;

    char* ws = (char*)d_ws;
    size_t off = 0;
    auto alloc = [&](size_t b) { size_t o = off; off = (off + b + 255) & ~(size_t)255; return o; };
    float* gpart          = (float*)(ws + alloc((size_t)8 * 512 * 256 * 4));      // 4.19 MB
    unsigned short* gn_bf = (unsigned short*)(ws + alloc((size_t)500 * 256 * 2));
    float* sim            = (float*)(ws + alloc((size_t)CLS * CLS * 4));          // 1 MB
    unsigned short* imgP  = (unsigned short*)(ws + alloc((size_t)2 * 256 * 1024 * 2));  // 1.05 MB
    unsigned short* asemP = (unsigned short*)(ws + alloc((size_t)2 * 512 * 1024 * 2));  // 2.1 MB
    unsigned short* sem_h = (unsigned short*)(ws + alloc((size_t)500 * 1024 * 2));      // 1 MB
    float* outP           = (float*)(ws + alloc((size_t)32 * BATCH * CLS * 4));   // 16.4 MB

    // N1: all independent GEMM partials in one dispatch (g / img / asem)
    mega_gemm<<<320, 256, 0, stream>>>(attrs, attg, imgf, imgw, semw,
                                       gpart, imgP, asemP);
    // N2: reduce 8 partials + row-normalize -> gn bf16
    reduce_norm_kernel<<<CLS, 256, 0, stream>>>(gpart, gn_bf);
    // N3: sim = gn @ gn^T [500,500] f32
    sim_kernel<<<dim3(8, 4), 256, 0, stream>>>(gn_bf, sim);
    // N4: masked softmax + gather asem (+semb) -> sem_h bf16
    softmax_gather_kernel<<<CLS, 256, 0, stream>>>(sim, asemP, semb, sem_h);
    // N5: fused relu-reduction -> outP[32][256][500]
    fused_out_partial<<<dim3(4, 8, 32), 256, 0, stream>>>(imgP, sem_h, fcw, outP);
    // N6: finalize (32 partials)
    finalize_kernel<<<(BATCH * CLS + 255) / 256, 256, 0, stream>>>(outP, fcb, out);
}